// Round 11
// baseline (357.434 us; speedup 1.0000x reference)
//
#include <hip/hip_runtime.h>
#include <hip/hip_bf16.h>

typedef __attribute__((ext_vector_type(8))) short bf16x8;
typedef __attribute__((ext_vector_type(8))) unsigned short ushort8;
typedef __attribute__((ext_vector_type(4))) float f32x4;
typedef unsigned int u32;

#define D_DIM 512
#define C_DIM 1024
#define B_DIM 65536

__device__ __forceinline__ unsigned short f2bf(float x) {
  u32 u = __float_as_uint(x);
  u32 r = (u + 0x7fffu + ((u >> 16) & 1u)) >> 16;
  return (unsigned short)r;
}

__device__ __forceinline__ void async16(const void* g, void* l) {
  __builtin_amdgcn_global_load_lds(
      (const __attribute__((address_space(1))) u32*)g,
      (__attribute__((address_space(3))) u32*)l, 16, 0, 0);
}

// sharp(x) = sigmoid(10x-5) + sigmoid(-10x-5)
//          = (E t^2 + 2t + 1) / (E t^2 + (1+E) t + 1),  t = e^(10x-5), E = e^10.
__device__ __forceinline__ float sharpf(float x) {
  float t = __expf(10.f * x - 5.f);
  float u = 22026.4658f * t * t;
  float num = u + 2.f * t + 1.f;
  float den = u + 22027.4658f * t + 1.f;
  return num * __builtin_amdgcn_rcpf(den);
}

// Normalize rows of length 512 (l2, +1e-12 eps) and cast to bf16.
__global__ __launch_bounds__(256) void rownorm_kernel(
    const float* __restrict__ src, unsigned short* __restrict__ dst) {
  int row = blockIdx.x * 4 + (threadIdx.x >> 6);
  int lane = threadIdx.x & 63;
  const float* s = src + (size_t)row * D_DIM + lane * 8;
  float4 v0 = *(const float4*)s;
  float4 v1 = *(const float4*)(s + 4);
  float ss = v0.x * v0.x + v0.y * v0.y + v0.z * v0.z + v0.w * v0.w +
             v1.x * v1.x + v1.y * v1.y + v1.z * v1.z + v1.w * v1.w;
#pragma unroll
  for (int m = 32; m >= 1; m >>= 1) ss += __shfl_xor(ss, m);
  float rinv = rsqrtf(ss + 1e-12f);
  float tv[8] = {v0.x, v0.y, v0.z, v0.w, v1.x, v1.y, v1.z, v1.w};
  ushort8 o;
#pragma unroll
  for (int i = 0; i < 8; ++i) o[i] = f2bf(tv[i] * rinv);
  *(ushort8*)(dst + (size_t)row * D_DIM + lane * 8) = o;
}

// vp packed: fragment (nt, g) at ((nt*32+g)*64+l)*8, element e =
// bf16(val[g*32+(l>>4)*8+e][nt*16+(l&15)]). One 32x32 val tile per block.
__global__ __launch_bounds__(256) void valTp_kernel(
    const float* __restrict__ val, unsigned short* __restrict__ vp) {
  __shared__ float tile[32][33];
  int bx = blockIdx.x & 31;  // n tile
  int by = blockIdx.x >> 5;  // k tile == g
  int t = threadIdx.x;
  int r = t >> 5, c = t & 31;
#pragma unroll
  for (int i = 0; i < 4; ++i)
    tile[r + i * 8][c] = val[(size_t)(by * 32 + r + i * 8) * C_DIM + bx * 32 + c];
  __syncthreads();
  if (t < 128) {
    int ntl = t >> 6;  // 0..1
    int l = t & 63;
    int nloc = ntl * 16 + (l & 15);
    int k0 = (l >> 4) * 8;
    ushort8 o;
#pragma unroll
    for (int e = 0; e < 8; ++e) o[e] = f2bf(tile[k0 + e][nloc]);
    size_t nt = bx * 2 + ntl;
    *(ushort8*)&vp[(nt * 32 + by) * 512 + (size_t)l * 8] = o;
  }
}

// rsum[i] = sum of the 4 per-n-block partials
__global__ __launch_bounds__(256) void rsum_reduce_kernel(
    const float* __restrict__ part, float* __restrict__ rsum) {
  int i = blockIdx.x * 256 + threadIdx.x;
  rsum[i] = (part[i] + part[i + B_DIM]) +
            (part[i + 2 * B_DIM] + part[i + 3 * B_DIM]);
}

// GEMM1: 256x256, BK=64, 8 waves (2Mx4N), r7 schedule (proven): head
// [vmcnt(6)|0; BAR]; ph0: reads(A band0 + all B) + stage(T+1,u3) + MFMA;
// ph1-3: reads(A band p) + BAR + stage(T+2,u p-1) + MFMA.
// Epilogue: sharp -> LDS scatter with swizzle col^((row&15)<<4) (conflict-free
// for scatter AND fragment-order re-read) -> PACKED w store (fragment (mt,g)
// = 1KB contiguous, lane l's bf16x8 at ((Mt*32+g)*64+l)*8) -> rowsum
// wc-reduce -> rsum_part.
__global__ __launch_bounds__(512, 2) void gemm1_kernel(
    const unsigned short* __restrict__ A, const unsigned short* __restrict__ Bm,
    unsigned short* __restrict__ wp, float* __restrict__ rsum) {
  __shared__ unsigned short smem[65536];  // 128 KB
  const int NKT = D_DIM / 64;
  const int bid = blockIdx.x;
  const int wg = (bid & 7) * 128 + (bid >> 3);
  const int m0 = (wg >> 2) * 256;
  const int n0 = (wg & 3) * 256;
  const int t = threadIdx.x;
  const int lane = t & 63;
  const int wv = t >> 6;
  const int wr = wv >> 2;
  const int wc = wv & 3;
  const int lo = lane & 15, hi = lane >> 4;
  const int swu = (lo & 7) << 3;

  const int s_ridx = t >> 3;
  const int s_c = (t & 7) * 8;
  auto stage = [&](int T, int k) {
    int r = (s_ridx < 32) ? (k * 32 + s_ridx) : (96 + k * 32 + s_ridx);
    int cl = s_c ^ ((r & 7) << 3);
    size_t go = (size_t)T * 64 + cl;
    int d = (T & 1) * 32768;
    async16(A + (size_t)(m0 + r) * D_DIM + go, &smem[d + r * 64 + s_c]);
    async16(Bm + (size_t)(n0 + r) * D_DIM + go, &smem[d + 16384 + r * 64 + s_c]);
  };

  f32x4 acc[8][4];
#pragma unroll
  for (int i = 0; i < 8; ++i)
#pragma unroll
    for (int j = 0; j < 4; ++j) acc[i][j] = (f32x4){0.f, 0.f, 0.f, 0.f};

  stage(0, 0); stage(0, 1); stage(0, 2); stage(0, 3);
  stage(1, 0); stage(1, 1); stage(1, 2);

#pragma unroll 1
  for (int T = 0; T < NKT; ++T) {
    if (T == NKT - 1) {
      asm volatile("s_waitcnt vmcnt(0)" ::: "memory");
    } else {
      asm volatile("s_waitcnt vmcnt(6)" ::: "memory");
    }
    __builtin_amdgcn_s_barrier();
    const int d = (T & 1) * 32768;
    bf16x8 bfr[4][2];
    {
      bf16x8 af[2][2];
#pragma unroll
      for (int mi = 0; mi < 2; ++mi)
#pragma unroll
        for (int ks = 0; ks < 2; ++ks) {
          int r = wr * 128 + mi * 16 + lo;
          af[mi][ks] = *(const bf16x8*)&smem[d + r * 64 + ((ks * 32 + hi * 8) ^ swu)];
        }
#pragma unroll
      for (int nf = 0; nf < 4; ++nf)
#pragma unroll
        for (int ks = 0; ks < 2; ++ks) {
          int r = wc * 64 + nf * 16 + lo;
          bfr[nf][ks] =
              *(const bf16x8*)&smem[d + 16384 + r * 64 + ((ks * 32 + hi * 8) ^ swu)];
        }
      if (T + 1 < NKT) stage(T + 1, 3);
      __builtin_amdgcn_s_setprio(1);
#pragma unroll
      for (int mi = 0; mi < 2; ++mi)
#pragma unroll
        for (int nf = 0; nf < 4; ++nf)
#pragma unroll
          for (int ks = 0; ks < 2; ++ks)
            acc[mi][nf] = __builtin_amdgcn_mfma_f32_16x16x32_bf16(
                af[mi][ks], bfr[nf][ks], acc[mi][nf], 0, 0, 0);
      __builtin_amdgcn_s_setprio(0);
    }
#pragma unroll
    for (int p = 1; p < 4; ++p) {
      bf16x8 af[2][2];
#pragma unroll
      for (int mi = 0; mi < 2; ++mi)
#pragma unroll
        for (int ks = 0; ks < 2; ++ks) {
          int r = wr * 128 + (p * 2 + mi) * 16 + lo;
          af[mi][ks] = *(const bf16x8*)&smem[d + r * 64 + ((ks * 32 + hi * 8) ^ swu)];
        }
      __builtin_amdgcn_s_barrier();
      if (T + 2 < NKT) stage(T + 2, p - 1);
      __builtin_amdgcn_s_setprio(1);
#pragma unroll
      for (int mi = 0; mi < 2; ++mi)
#pragma unroll
        for (int nf = 0; nf < 4; ++nf)
#pragma unroll
          for (int ks = 0; ks < 2; ++ks)
            acc[p * 2 + mi][nf] = __builtin_amdgcn_mfma_f32_16x16x32_bf16(
                af[mi][ks], bfr[nf][ks], acc[p * 2 + mi][nf], 0, 0, 0);
      __builtin_amdgcn_s_setprio(0);
    }
  }
  __syncthreads();

  // ---- epilogue ----
  float rs[8][4];
#pragma unroll
  for (int i = 0; i < 8; ++i)
#pragma unroll
    for (int j = 0; j < 4; ++j) rs[i][j] = 0.f;
  unsigned short* ep = smem;  // 256x256 u16
#pragma unroll
  for (int mf = 0; mf < 8; ++mf)
#pragma unroll
    for (int nf = 0; nf < 4; ++nf)
#pragma unroll
      for (int j = 0; j < 4; ++j) {
        float s = sharpf(acc[mf][nf][j]);
        rs[mf][j] += s;
        int rl = wr * 128 + mf * 16 + (hi << 2) + j;
        int cl = (wc * 64 + nf * 16 + lo) ^ ((rl & 15) << 4);
        ep[rl * 256 + cl] = f2bf(s);
      }
#pragma unroll
  for (int mf = 0; mf < 8; ++mf)
#pragma unroll
    for (int j = 0; j < 4; ++j) {
      float v = rs[mf][j];
      v += __shfl_xor(v, 1);
      v += __shfl_xor(v, 2);
      v += __shfl_xor(v, 4);
      v += __shfl_xor(v, 8);
      rs[mf][j] = v;
    }
  __syncthreads();
  // packed fragment-order store: (mt, g=wv) -> 1 KB contiguous
#pragma unroll
  for (int mt = 0; mt < 16; ++mt) {
    int prow = mt * 16 + (lane & 15);
    int pcol = (wv * 32 + hi * 8) ^ ((lane & 15) << 4);
    ushort8 v = *(const ushort8*)&ep[prow * 256 + pcol];
    size_t off = (((size_t)(m0 >> 4) + mt) * 32 + (n0 >> 5) + wv) * 512 +
                 (size_t)lane * 8;
    *(ushort8*)&wp[off] = v;
  }
  __syncthreads();
  float* rbuf = (float*)smem;  // [4][256]
  if (lo == 0) {
#pragma unroll
    for (int mf = 0; mf < 8; ++mf)
#pragma unroll
      for (int j = 0; j < 4; ++j)
        rbuf[wc * 256 + wr * 128 + mf * 16 + (hi << 2) + j] = rs[mf][j];
  }
  __syncthreads();
  if (t < 256) {
    float v = (rbuf[t] + rbuf[256 + t]) + (rbuf[512 + t] + rbuf[768 + t]);
    rsum[(size_t)(wg & 3) * B_DIM + m0 + t] = v;
  }
}

// GEMM2: out = (w/rsum) @ vbT^T via packed fragments. NO LDS, NO barriers.
// 8 waves (2Mx4N), per-wave 128x64, acc 128 f32. Per K-tile: 8 af + 8 bfr
// coalesced 1KB loads -> 32 MFMA -> reload af (mf4..7, regs reused) -> 32
// MFMA. Compiler scoreboards the waits; waves drift to mutually hide L2/L3
// latency. Regs ~217 < 256 (2 waves/SIMD).
__global__ __launch_bounds__(512, 2) void gemm2_kernel(
    const unsigned short* __restrict__ wp, const unsigned short* __restrict__ vp,
    const float* __restrict__ rsum, float* __restrict__ fout) {
  const int bid = blockIdx.x;
  const int wg = (bid & 7) * 128 + (bid >> 3);
  const int m0 = (wg >> 2) * 256;
  const int n0 = (wg & 3) * 256;
  const int t = threadIdx.x;
  const int lane = t & 63;
  const int wv = t >> 6;
  const int wr = wv >> 2;
  const int wc = wv & 3;
  const int lo = lane & 15, hi = lane >> 4;

  f32x4 acc[8][4];
#pragma unroll
  for (int i = 0; i < 8; ++i)
#pragma unroll
    for (int j = 0; j < 4; ++j) acc[i][j] = (f32x4){0.f, 0.f, 0.f, 0.f};

  const unsigned short* pa =
      wp + (((size_t)(m0 >> 4) + wr * 8) * 32) * 512 + (size_t)lane * 8;
  const unsigned short* pb =
      vp + (((size_t)(n0 >> 4) + wc * 4) * 32) * 512 + (size_t)lane * 8;

#pragma unroll 1
  for (int T = 0; T < 16; ++T) {
    bf16x8 af[4][2], bfr[4][2];
#pragma unroll
    for (int mf = 0; mf < 4; ++mf)
#pragma unroll
      for (int ks = 0; ks < 2; ++ks)
        af[mf][ks] = *(const bf16x8*)(pa + ((size_t)mf * 32 + T * 2 + ks) * 512);
#pragma unroll
    for (int nf = 0; nf < 4; ++nf)
#pragma unroll
      for (int ks = 0; ks < 2; ++ks)
        bfr[nf][ks] = *(const bf16x8*)(pb + ((size_t)nf * 32 + T * 2 + ks) * 512);
    __builtin_amdgcn_s_setprio(1);
#pragma unroll
    for (int mf = 0; mf < 4; ++mf)
#pragma unroll
      for (int nf = 0; nf < 4; ++nf)
#pragma unroll
        for (int ks = 0; ks < 2; ++ks)
          acc[mf][nf] = __builtin_amdgcn_mfma_f32_16x16x32_bf16(
              af[mf][ks], bfr[nf][ks], acc[mf][nf], 0, 0, 0);
    __builtin_amdgcn_s_setprio(0);
#pragma unroll
    for (int mf = 0; mf < 4; ++mf)
#pragma unroll
      for (int ks = 0; ks < 2; ++ks)
        af[mf][ks] =
            *(const bf16x8*)(pa + ((size_t)(mf + 4) * 32 + T * 2 + ks) * 512);
    __builtin_amdgcn_s_setprio(1);
#pragma unroll
    for (int mf = 0; mf < 4; ++mf)
#pragma unroll
      for (int nf = 0; nf < 4; ++nf)
#pragma unroll
        for (int ks = 0; ks < 2; ++ks)
          acc[4 + mf][nf] = __builtin_amdgcn_mfma_f32_16x16x32_bf16(
              af[mf][ks], bfr[nf][ks], acc[4 + mf][nf], 0, 0, 0);
    __builtin_amdgcn_s_setprio(0);
  }

  float rinv[8][4];
#pragma unroll
  for (int mf = 0; mf < 8; ++mf) {
    float4 r4 = *(const float4*)&rsum[m0 + wr * 128 + mf * 16 + (hi << 2)];
    rinv[mf][0] = __builtin_amdgcn_rcpf(r4.x);
    rinv[mf][1] = __builtin_amdgcn_rcpf(r4.y);
    rinv[mf][2] = __builtin_amdgcn_rcpf(r4.z);
    rinv[mf][3] = __builtin_amdgcn_rcpf(r4.w);
  }
#pragma unroll
  for (int mf = 0; mf < 8; ++mf)
#pragma unroll
    for (int nf = 0; nf < 4; ++nf)
#pragma unroll
      for (int j = 0; j < 4; ++j)
        fout[(size_t)(m0 + wr * 128 + mf * 16 + (hi << 2) + j) * C_DIM +
             n0 + wc * 64 + nf * 16 + lo] = acc[mf][nf][j] * rinv[mf][j];
}

extern "C" void kernel_launch(void* const* d_in, const int* in_sizes, int n_in,
                              void* d_out, int out_size, void* d_ws, size_t ws_size,
                              hipStream_t stream) {
  const float* query = (const float*)d_in[0];
  const float* key = (const float*)d_in[1];
  const float* val = (const float*)d_in[2];
  float* out = (float*)d_out;
  const int B = in_sizes[0] / D_DIM;  // 65536

  char* ws = (char*)d_ws;
  unsigned short* kb = (unsigned short*)(ws);                         // 1 MB
  unsigned short* vp = (unsigned short*)(ws + (1ull << 20));          // 2 MB
  float* rsum_part = (float*)(ws + 3ull * (1ull << 20));              // 1 MB
  unsigned short* qb = (unsigned short*)(ws + 4ull * (1ull << 20));   // 64 MB
  float* rsum = (float*)qb;  // reuses qb region (dead after GEMM1)
  unsigned short* wp = (unsigned short*)(ws + 68ull * (1ull << 20));  // 128 MB

  rownorm_kernel<<<dim3(B / 4), dim3(256), 0, stream>>>(query, qb);
  rownorm_kernel<<<dim3(C_DIM / 4), dim3(256), 0, stream>>>(key, kb);
  valTp_kernel<<<dim3(1024), dim3(256), 0, stream>>>(val, vp);

  dim3 grid((B / 256) * (C_DIM / 256));  // 1024 blocks
  gemm1_kernel<<<grid, dim3(512), 0, stream>>>(qb, kb, wp, rsum_part);
  rsum_reduce_kernel<<<dim3(B / 256), dim3(256), 0, stream>>>(rsum_part, rsum);
  gemm2_kernel<<<grid, dim3(512), 0, stream>>>(wp, vp, rsum, out);
}

// Round 12
// 350.989 us; speedup vs baseline: 1.0184x; 1.0184x over previous
//
#include <hip/hip_runtime.h>
#include <hip/hip_bf16.h>

typedef __attribute__((ext_vector_type(8))) short bf16x8;
typedef __attribute__((ext_vector_type(8))) unsigned short ushort8;
typedef __attribute__((ext_vector_type(4))) float f32x4;
typedef unsigned int u32;

#define D_DIM 512
#define C_DIM 1024
#define B_DIM 65536

__device__ __forceinline__ unsigned short f2bf(float x) {
  u32 u = __float_as_uint(x);
  u32 r = (u + 0x7fffu + ((u >> 16) & 1u)) >> 16;
  return (unsigned short)r;
}

__device__ __forceinline__ void async16(const void* g, void* l) {
  __builtin_amdgcn_global_load_lds(
      (const __attribute__((address_space(1))) u32*)g,
      (__attribute__((address_space(3))) u32*)l, 16, 0, 0);
}

// sharp(x) = sigmoid(10x-5) + sigmoid(-10x-5)
//          = (E t^2 + 2t + 1) / (E t^2 + (1+E) t + 1),  t = e^(10x-5), E = e^10.
__device__ __forceinline__ float sharpf(float x) {
  float t = __expf(10.f * x - 5.f);
  float u = 22026.4658f * t * t;
  float num = u + 2.f * t + 1.f;
  float den = u + 22027.4658f * t + 1.f;
  return num * __builtin_amdgcn_rcpf(den);
}

// Fused prep: blocks [0,16384) rownorm q; [16384,16640) rownorm k;
// [16640,17664) val transpose+cast. Branch is block-uniform.
__global__ __launch_bounds__(256) void prep_kernel(
    const float* __restrict__ q, const float* __restrict__ k,
    const float* __restrict__ val, unsigned short* __restrict__ qb,
    unsigned short* __restrict__ kb, unsigned short* __restrict__ vbT) {
  __shared__ float tile[32][33];
  int bid = blockIdx.x;
  if (bid < 16640) {
    const float* src = (bid < 16384) ? q : k;
    unsigned short* dst = (bid < 16384) ? qb : kb;
    int b = (bid < 16384) ? bid : bid - 16384;
    int row = b * 4 + (threadIdx.x >> 6);
    int lane = threadIdx.x & 63;
    const float* s = src + (size_t)row * D_DIM + lane * 8;
    float4 v0 = *(const float4*)s;
    float4 v1 = *(const float4*)(s + 4);
    float ss = v0.x * v0.x + v0.y * v0.y + v0.z * v0.z + v0.w * v0.w +
               v1.x * v1.x + v1.y * v1.y + v1.z * v1.z + v1.w * v1.w;
#pragma unroll
    for (int m = 32; m >= 1; m >>= 1) ss += __shfl_xor(ss, m);
    float rinv = rsqrtf(ss + 1e-12f);
    float tv[8] = {v0.x, v0.y, v0.z, v0.w, v1.x, v1.y, v1.z, v1.w};
    ushort8 o;
#pragma unroll
    for (int i = 0; i < 8; ++i) o[i] = f2bf(tv[i] * rinv);
    *(ushort8*)(dst + (size_t)row * D_DIM + lane * 8) = o;
  } else {
    int b = bid - 16640;
    int bx = b & 31;  // n tile
    int by = b >> 5;  // k tile
    int t = threadIdx.x;
    int r = t >> 5, c = t & 31;
#pragma unroll
    for (int i = 0; i < 4; ++i)
      tile[r + i * 8][c] = val[(size_t)(by * 32 + r + i * 8) * C_DIM + bx * 32 + c];
    __syncthreads();
#pragma unroll
    for (int i = 0; i < 4; ++i)
      vbT[(size_t)(bx * 32 + r + i * 8) * C_DIM + by * 32 + c] =
          f2bf(tile[c][r + i * 8]);
  }
}

// GEMM1 (r7-proven): 256x256, BK=64, 8 waves (2Mx4N). Head [vmcnt(6)|0; BAR];
// ph0: reads(A band0 + all B) + stage(T+1,u3) + 16 MFMA; ph1-3: reads(A band
// p) + BAR + stage(T+2,u p-1) + 16 MFMA. Epilogue: sharp -> conflict-free
// swizzled LDS scatter -> coalesced 16B w store -> wc-reduce rowsums ->
// rsum_part[n][row].
__global__ __launch_bounds__(512, 2) void gemm1_kernel(
    const unsigned short* __restrict__ A, const unsigned short* __restrict__ Bm,
    unsigned short* __restrict__ wout, float* __restrict__ rsum) {
  __shared__ unsigned short smem[65536];  // 128 KB
  const int NKT = D_DIM / 64;
  const int bid = blockIdx.x;
  const int wg = (bid & 7) * 128 + (bid >> 3);  // nwg=1024
  const int m0 = (wg >> 2) * 256;
  const int n0 = (wg & 3) * 256;
  const int t = threadIdx.x;
  const int lane = t & 63;
  const int wv = t >> 6;
  const int wr = wv >> 2;
  const int wc = wv & 3;
  const int lo = lane & 15, hi = lane >> 4;
  const int swu = (lo & 7) << 3;

  const int s_ridx = t >> 3;
  const int s_c = (t & 7) * 8;
  auto stage = [&](int T, int k) {
    int r = (s_ridx < 32) ? (k * 32 + s_ridx) : (96 + k * 32 + s_ridx);
    int cl = s_c ^ ((r & 7) << 3);
    size_t go = (size_t)T * 64 + cl;
    int d = (T & 1) * 32768;
    async16(A + (size_t)(m0 + r) * D_DIM + go, &smem[d + r * 64 + s_c]);
    async16(Bm + (size_t)(n0 + r) * D_DIM + go, &smem[d + 16384 + r * 64 + s_c]);
  };

  f32x4 acc[8][4];
#pragma unroll
  for (int i = 0; i < 8; ++i)
#pragma unroll
    for (int j = 0; j < 4; ++j) acc[i][j] = (f32x4){0.f, 0.f, 0.f, 0.f};

  stage(0, 0); stage(0, 1); stage(0, 2); stage(0, 3);
  stage(1, 0); stage(1, 1); stage(1, 2);

#pragma unroll 1
  for (int T = 0; T < NKT; ++T) {
    if (T == NKT - 1) {
      asm volatile("s_waitcnt vmcnt(0)" ::: "memory");
    } else {
      asm volatile("s_waitcnt vmcnt(6)" ::: "memory");
    }
    __builtin_amdgcn_s_barrier();
    const int d = (T & 1) * 32768;
    bf16x8 bfr[4][2];
    {
      bf16x8 af[2][2];
#pragma unroll
      for (int mi = 0; mi < 2; ++mi)
#pragma unroll
        for (int ks = 0; ks < 2; ++ks) {
          int r = wr * 128 + mi * 16 + lo;
          af[mi][ks] = *(const bf16x8*)&smem[d + r * 64 + ((ks * 32 + hi * 8) ^ swu)];
        }
#pragma unroll
      for (int nf = 0; nf < 4; ++nf)
#pragma unroll
        for (int ks = 0; ks < 2; ++ks) {
          int r = wc * 64 + nf * 16 + lo;
          bfr[nf][ks] =
              *(const bf16x8*)&smem[d + 16384 + r * 64 + ((ks * 32 + hi * 8) ^ swu)];
        }
      if (T + 1 < NKT) stage(T + 1, 3);
      __builtin_amdgcn_s_setprio(1);
#pragma unroll
      for (int mi = 0; mi < 2; ++mi)
#pragma unroll
        for (int nf = 0; nf < 4; ++nf)
#pragma unroll
          for (int ks = 0; ks < 2; ++ks)
            acc[mi][nf] = __builtin_amdgcn_mfma_f32_16x16x32_bf16(
                af[mi][ks], bfr[nf][ks], acc[mi][nf], 0, 0, 0);
      __builtin_amdgcn_s_setprio(0);
    }
#pragma unroll
    for (int p = 1; p < 4; ++p) {
      bf16x8 af[2][2];
#pragma unroll
      for (int mi = 0; mi < 2; ++mi)
#pragma unroll
        for (int ks = 0; ks < 2; ++ks) {
          int r = wr * 128 + (p * 2 + mi) * 16 + lo;
          af[mi][ks] = *(const bf16x8*)&smem[d + r * 64 + ((ks * 32 + hi * 8) ^ swu)];
        }
      __builtin_amdgcn_s_barrier();
      if (T + 2 < NKT) stage(T + 2, p - 1);
      __builtin_amdgcn_s_setprio(1);
#pragma unroll
      for (int mi = 0; mi < 2; ++mi)
#pragma unroll
        for (int nf = 0; nf < 4; ++nf)
#pragma unroll
          for (int ks = 0; ks < 2; ++ks)
            acc[p * 2 + mi][nf] = __builtin_amdgcn_mfma_f32_16x16x32_bf16(
                af[mi][ks], bfr[nf][ks], acc[p * 2 + mi][nf], 0, 0, 0);
      __builtin_amdgcn_s_setprio(0);
    }
  }
  __syncthreads();

  float rs[8][4];
#pragma unroll
  for (int i = 0; i < 8; ++i)
#pragma unroll
    for (int j = 0; j < 4; ++j) rs[i][j] = 0.f;
  unsigned short* ep = smem;
#pragma unroll
  for (int mf = 0; mf < 8; ++mf)
#pragma unroll
    for (int nf = 0; nf < 4; ++nf)
#pragma unroll
      for (int j = 0; j < 4; ++j) {
        float s = sharpf(acc[mf][nf][j]);
        rs[mf][j] += s;
        int rl = wr * 128 + mf * 16 + (hi << 2) + j;
        int cl = (wc * 64 + nf * 16 + lo) ^ (((rl >> 2) & 3) << 4);
        ep[rl * 256 + cl] = f2bf(s);
      }
#pragma unroll
  for (int mf = 0; mf < 8; ++mf)
#pragma unroll
    for (int j = 0; j < 4; ++j) {
      float v = rs[mf][j];
      v += __shfl_xor(v, 1);
      v += __shfl_xor(v, 2);
      v += __shfl_xor(v, 4);
      v += __shfl_xor(v, 8);
      rs[mf][j] = v;
    }
  __syncthreads();
#pragma unroll
  for (int pass = 0; pass < 16; ++pass) {
    int idx = pass * 4096 + t * 8;
    int row = idx >> 8, col = idx & 255;
    int phys = row * 256 + (col ^ (((row >> 2) & 3) << 4));
    *(ushort8*)&wout[(size_t)(m0 + row) * C_DIM + n0 + col] =
        *(const ushort8*)&ep[phys];
  }
  __syncthreads();
  float* rbuf = (float*)smem;  // [4][256]
  if (lo == 0) {
#pragma unroll
    for (int mf = 0; mf < 8; ++mf)
#pragma unroll
      for (int j = 0; j < 4; ++j)
        rbuf[wc * 256 + wr * 128 + mf * 16 + (hi << 2) + j] = rs[mf][j];
  }
  __syncthreads();
  if (t < 256) {
    float v = (rbuf[t] + rbuf[256 + t]) + (rbuf[512 + t] + rbuf[768 + t]);
    rsum[(size_t)(wg & 3) * B_DIM + m0 + t] = v;
  }
}

// GEMM2: 256x128 tile, BK=32, 256 thr = 4 waves (2Mx2N), per-wave 128x64
// (8mf x 4nf 16x16x32). 48 KB LDS -> 2 independent blocks/CU: the 2 waves on
// each SIMD come from DIFFERENT blocks, so barriers don't lockstep the SIMD.
// Staggered counted-vmcnt (r7 ledger): units u_b0B = A rows {0-63,128-191} +
// all B (4 loads/thr, read in ph0); u_b1 = A rows {64-127,192-255} (2 loads/
// thr, read in ph1). head: vmcnt(4) (last tile 0); BAR. ph0: reads af0-3 +
// bfr0-3, stage u_b1(T+1) [other buf], 16 MFMA. ph1: reads af4-7, BAR, stage
// u_b0B(T+2) [curr buf rows whose readers retired before this BAR], 16 MFMA.
// Swizzle for 64B rows: col ^= (r&3)<<3 (4 slots; r10-measured 0 conflicts).
// Epilogue: rinv = rcp(sum of 4 partials) inline (replaces reduce kernel).
__global__ __launch_bounds__(256, 2) void gemm2_kernel(
    const unsigned short* __restrict__ A, const unsigned short* __restrict__ Bm,
    const float* __restrict__ part, float* __restrict__ fout) {
  __shared__ unsigned short smem[24576];  // 48 KB: buf d: A[256][32] @d, B[128][32] @d+8192
  const int NKT = C_DIM / 32;             // 32
  const int bid = blockIdx.x;
  const int wg = (bid & 7) * 256 + (bid >> 3);  // nwg=2048
  const int m0 = (wg >> 3) * 256;
  const int n0 = (wg & 7) * 128;
  const int t = threadIdx.x;
  const int lane = t & 63;
  const int wv = t >> 6;   // 0..3
  const int wr = wv >> 1;  // 0..1
  const int wc = wv & 1;   // 0..1
  const int lo = lane & 15, hi = lane >> 4;

  auto stage_b1 = [&](int T) {  // A rows {64..127, 192..255}: 2 loads/thr
    const int d = (T & 1) * 12288;
#pragma unroll
    for (int i = 0; i < 2; ++i) {
      int s = i * 256 + t;
      int rl = s >> 2;
      int r = 64 + (rl & 63) + (rl >> 6) * 128;
      int sc = (s & 3) * 8;
      int cl = sc ^ ((r & 3) << 3);
      async16(A + (size_t)(m0 + r) * C_DIM + (size_t)T * 32 + cl,
              &smem[d + r * 32 + sc]);
    }
  };
  auto stage_b0B = [&](int T) {  // A rows {0..63, 128..191} + all B: 4 loads/thr
    const int d = (T & 1) * 12288;
#pragma unroll
    for (int i = 0; i < 2; ++i) {
      int s = i * 256 + t;
      int rl = s >> 2;
      int r = (rl & 63) + (rl >> 6) * 128;
      int sc = (s & 3) * 8;
      int cl = sc ^ ((r & 3) << 3);
      async16(A + (size_t)(m0 + r) * C_DIM + (size_t)T * 32 + cl,
              &smem[d + r * 32 + sc]);
    }
#pragma unroll
    for (int i = 0; i < 2; ++i) {
      int s = i * 256 + t;
      int n = s >> 2;
      int sc = (s & 3) * 8;
      int cl = sc ^ ((n & 3) << 3);
      async16(Bm + (size_t)(n0 + n) * C_DIM + (size_t)T * 32 + cl,
              &smem[d + 8192 + n * 32 + sc]);
    }
  };

  f32x4 acc[8][4];
#pragma unroll
  for (int i = 0; i < 8; ++i)
#pragma unroll
    for (int j = 0; j < 4; ++j) acc[i][j] = (f32x4){0.f, 0.f, 0.f, 0.f};

  stage_b0B(0); stage_b1(0); stage_b0B(1);  // 10 loads in flight

#pragma unroll 1
  for (int T = 0; T < NKT; ++T) {
    if (T == NKT - 1) {
      asm volatile("s_waitcnt vmcnt(0)" ::: "memory");
    } else {
      asm volatile("s_waitcnt vmcnt(4)" ::: "memory");
    }
    __builtin_amdgcn_s_barrier();
    const int d = (T & 1) * 12288;
    bf16x8 bfr[4];
    {  // phase 0: af 0..3 + all bfr; stage u_b1(T+1); MFMA mf0-3
      bf16x8 af[4];
#pragma unroll
      for (int mf = 0; mf < 4; ++mf) {
        int r = wr * 128 + mf * 16 + lo;
        af[mf] = *(const bf16x8*)&smem[d + r * 32 + ((hi * 8) ^ ((r & 3) << 3))];
      }
#pragma unroll
      for (int nf = 0; nf < 4; ++nf) {
        int n = wc * 64 + nf * 16 + lo;
        bfr[nf] =
            *(const bf16x8*)&smem[d + 8192 + n * 32 + ((hi * 8) ^ ((n & 3) << 3))];
      }
      if (T + 1 < NKT) stage_b1(T + 1);
      __builtin_amdgcn_s_setprio(1);
#pragma unroll
      for (int mf = 0; mf < 4; ++mf)
#pragma unroll
        for (int nf = 0; nf < 4; ++nf)
          acc[mf][nf] = __builtin_amdgcn_mfma_f32_16x16x32_bf16(
              af[mf], bfr[nf], acc[mf][nf], 0, 0, 0);
      __builtin_amdgcn_s_setprio(0);
    }
    {  // phase 1: af 4..7; BAR; stage u_b0B(T+2); MFMA mf4-7
      bf16x8 af[4];
#pragma unroll
      for (int mf = 0; mf < 4; ++mf) {
        int r = wr * 128 + (4 + mf) * 16 + lo;
        af[mf] = *(const bf16x8*)&smem[d + r * 32 + ((hi * 8) ^ ((r & 3) << 3))];
      }
      __builtin_amdgcn_s_barrier();
      if (T + 2 < NKT) stage_b0B(T + 2);
      __builtin_amdgcn_s_setprio(1);
#pragma unroll
      for (int mf = 0; mf < 4; ++mf)
#pragma unroll
        for (int nf = 0; nf < 4; ++nf)
          acc[4 + mf][nf] = __builtin_amdgcn_mfma_f32_16x16x32_bf16(
              af[mf], bfr[nf], acc[4 + mf][nf], 0, 0, 0);
      __builtin_amdgcn_s_setprio(0);
    }
  }

  // epilogue: rinv from the 4 rowsum partials (L2-hot), scattered f32 stores
  float rinv[8][4];
#pragma unroll
  for (int mf = 0; mf < 8; ++mf) {
    int base = m0 + wr * 128 + mf * 16 + (hi << 2);
    float4 p0 = *(const float4*)&part[base];
    float4 p1 = *(const float4*)&part[B_DIM + base];
    float4 p2 = *(const float4*)&part[2 * B_DIM + base];
    float4 p3 = *(const float4*)&part[3 * B_DIM + base];
    rinv[mf][0] = __builtin_amdgcn_rcpf((p0.x + p1.x) + (p2.x + p3.x));
    rinv[mf][1] = __builtin_amdgcn_rcpf((p0.y + p1.y) + (p2.y + p3.y));
    rinv[mf][2] = __builtin_amdgcn_rcpf((p0.z + p1.z) + (p2.z + p3.z));
    rinv[mf][3] = __builtin_amdgcn_rcpf((p0.w + p1.w) + (p2.w + p3.w));
  }
#pragma unroll
  for (int mf = 0; mf < 8; ++mf)
#pragma unroll
    for (int nf = 0; nf < 4; ++nf)
#pragma unroll
      for (int j = 0; j < 4; ++j)
        fout[(size_t)(m0 + wr * 128 + mf * 16 + (hi << 2) + j) * C_DIM +
             n0 + wc * 64 + nf * 16 + lo] = acc[mf][nf][j] * rinv[mf][j];
}

extern "C" void kernel_launch(void* const* d_in, const int* in_sizes, int n_in,
                              void* d_out, int out_size, void* d_ws, size_t ws_size,
                              hipStream_t stream) {
  const float* query = (const float*)d_in[0];
  const float* key = (const float*)d_in[1];
  const float* val = (const float*)d_in[2];
  float* out = (float*)d_out;
  const int B = in_sizes[0] / D_DIM;  // 65536

  char* ws = (char*)d_ws;
  unsigned short* kb = (unsigned short*)(ws);                         // 1 MB
  unsigned short* vbT = (unsigned short*)(ws + (1ull << 20));         // 2 MB
  float* rsum_part = (float*)(ws + 3ull * (1ull << 20));              // 1 MB
  unsigned short* qb = (unsigned short*)(ws + 4ull * (1ull << 20));   // 64 MB
  unsigned short* wbf = (unsigned short*)(ws + 68ull * (1ull << 20)); // 128 MB

  prep_kernel<<<dim3(17664), dim3(256), 0, stream>>>(query, key, val, qb, kb, vbT);
  gemm1_kernel<<<dim3((B / 256) * (C_DIM / 256)), dim3(512), 0, stream>>>(
      qb, kb, wbf, rsum_part);
  gemm2_kernel<<<dim3((B / 256) * (C_DIM / 128)), dim3(256), 0, stream>>>(
      wbf, vbT, rsum_part, out);
}

// Round 13
// 326.401 us; speedup vs baseline: 1.0951x; 1.0753x over previous
//
#include <hip/hip_runtime.h>
#include <hip/hip_bf16.h>

typedef __attribute__((ext_vector_type(8))) short bf16x8;
typedef __attribute__((ext_vector_type(8))) unsigned short ushort8;
typedef __attribute__((ext_vector_type(4))) float f32x4;
typedef unsigned int u32;

#define D_DIM 512
#define C_DIM 1024
#define B_DIM 65536

__device__ __forceinline__ unsigned short f2bf(float x) {
  u32 u = __float_as_uint(x);
  u32 r = (u + 0x7fffu + ((u >> 16) & 1u)) >> 16;
  return (unsigned short)r;
}

__device__ __forceinline__ void async16(const void* g, void* l) {
  __builtin_amdgcn_global_load_lds(
      (const __attribute__((address_space(1))) u32*)g,
      (__attribute__((address_space(3))) u32*)l, 16, 0, 0);
}

// sharp(x) = sigmoid(10x-5) + sigmoid(-10x-5)
//          = (E t^2 + 2t + 1) / (E t^2 + (1+E) t + 1),  t = e^(10x-5), E = e^10.
__device__ __forceinline__ float sharpf(float x) {
  float t = __expf(10.f * x - 5.f);
  float u = 22026.4658f * t * t;
  float num = u + 2.f * t + 1.f;
  float den = u + 22027.4658f * t + 1.f;
  return num * __builtin_amdgcn_rcpf(den);
}

// Fused prep: blocks [0,16384) rownorm q; [16384,16640) rownorm k;
// [16640,17664) val transpose+cast. Branch is block-uniform.
__global__ __launch_bounds__(256) void prep_kernel(
    const float* __restrict__ q, const float* __restrict__ k,
    const float* __restrict__ val, unsigned short* __restrict__ qb,
    unsigned short* __restrict__ kb, unsigned short* __restrict__ vbT) {
  __shared__ float tile[32][33];
  int bid = blockIdx.x;
  if (bid < 16640) {
    const float* src = (bid < 16384) ? q : k;
    unsigned short* dst = (bid < 16384) ? qb : kb;
    int b = (bid < 16384) ? bid : bid - 16384;
    int row = b * 4 + (threadIdx.x >> 6);
    int lane = threadIdx.x & 63;
    const float* s = src + (size_t)row * D_DIM + lane * 8;
    float4 v0 = *(const float4*)s;
    float4 v1 = *(const float4*)(s + 4);
    float ss = v0.x * v0.x + v0.y * v0.y + v0.z * v0.z + v0.w * v0.w +
               v1.x * v1.x + v1.y * v1.y + v1.z * v1.z + v1.w * v1.w;
#pragma unroll
    for (int m = 32; m >= 1; m >>= 1) ss += __shfl_xor(ss, m);
    float rinv = rsqrtf(ss + 1e-12f);
    float tv[8] = {v0.x, v0.y, v0.z, v0.w, v1.x, v1.y, v1.z, v1.w};
    ushort8 o;
#pragma unroll
    for (int i = 0; i < 8; ++i) o[i] = f2bf(tv[i] * rinv);
    *(ushort8*)(dst + (size_t)row * D_DIM + lane * 8) = o;
  } else {
    int b = bid - 16640;
    int bx = b & 31;  // n tile
    int by = b >> 5;  // k tile
    int t = threadIdx.x;
    int r = t >> 5, c = t & 31;
#pragma unroll
    for (int i = 0; i < 4; ++i)
      tile[r + i * 8][c] = val[(size_t)(by * 32 + r + i * 8) * C_DIM + bx * 32 + c];
    __syncthreads();
#pragma unroll
    for (int i = 0; i < 4; ++i)
      vbT[(size_t)(bx * 32 + r + i * 8) * C_DIM + by * 32 + c] =
          f2bf(tile[c][r + i * 8]);
  }
}

// 256x256 GEMM, BK=64, 8 waves (2Mx4N), per-wave 128x64 (8mf x 4nf 16x16x32).
// r7-proven schedule: head [vmcnt(6) | vmcnt(0) last; BAR]; ph0: reads(A band0
// + all B) + stage(T+1,u3) + 16 MFMA; ph1-3: reads(A band p) + BAR +
// stage(T+2,u p-1) + 16 MFMA. One barrier per phase; vmcnt never drains in
// the main loop. LDS rows 128B, XOR swizzle (lo&7)<<3 (0 conflicts measured).
// SHARP epilogue: sharp -> conflict-free swizzled LDS scatter (phys col ^=
// ((rl>>2)&3)<<4) -> coalesced 16B w store -> wc-reduce rowsums ->
// rsum_part[n][row].  !SHARP: rinv = rcp(sum of 4 partials) inline, f32 store.
template <int K, bool SHARP>
__global__ __launch_bounds__(512, 2) void gemm256_kernel(
    const unsigned short* __restrict__ A, const unsigned short* __restrict__ Bm,
    unsigned short* __restrict__ wout, float* __restrict__ rsum,
    float* __restrict__ fout) {
  __shared__ unsigned short smem[65536];  // 128 KB
  const int NKT = K / 64;
  const int bid = blockIdx.x;
  // XCD-chunked bijective swizzle: nwg=1024, 8 XCDs, 128 per chunk.
  const int wg = (bid & 7) * 128 + (bid >> 3);
  const int m0 = (wg >> 2) * 256;
  const int n0 = (wg & 3) * 256;
  const int t = threadIdx.x;
  const int lane = t & 63;
  const int wv = t >> 6;
  const int wr = wv >> 2;
  const int wc = wv & 3;
  const int lo = lane & 15, hi = lane >> 4;
  const int swu = (lo & 7) << 3;

  const int s_ridx = t >> 3;
  const int s_c = (t & 7) * 8;
  auto stage = [&](int T, int k) {
    int r = (s_ridx < 32) ? (k * 32 + s_ridx) : (96 + k * 32 + s_ridx);
    int cl = s_c ^ ((r & 7) << 3);
    size_t go = (size_t)T * 64 + cl;
    int d = (T & 1) * 32768;
    async16(A + (size_t)(m0 + r) * K + go, &smem[d + r * 64 + s_c]);
    async16(Bm + (size_t)(n0 + r) * K + go, &smem[d + 16384 + r * 64 + s_c]);
  };

  f32x4 acc[8][4];
#pragma unroll
  for (int i = 0; i < 8; ++i)
#pragma unroll
    for (int j = 0; j < 4; ++j) acc[i][j] = (f32x4){0.f, 0.f, 0.f, 0.f};

  stage(0, 0); stage(0, 1); stage(0, 2); stage(0, 3);
  stage(1, 0); stage(1, 1); stage(1, 2);

#pragma unroll 1
  for (int T = 0; T < NKT; ++T) {
    if (T == NKT - 1) {
      asm volatile("s_waitcnt vmcnt(0)" ::: "memory");
    } else {
      asm volatile("s_waitcnt vmcnt(6)" ::: "memory");
    }
    __builtin_amdgcn_s_barrier();
    const int d = (T & 1) * 32768;
    bf16x8 bfr[4][2];
    {  // phase 0
      bf16x8 af[2][2];
#pragma unroll
      for (int mi = 0; mi < 2; ++mi)
#pragma unroll
        for (int ks = 0; ks < 2; ++ks) {
          int r = wr * 128 + mi * 16 + lo;
          af[mi][ks] = *(const bf16x8*)&smem[d + r * 64 + ((ks * 32 + hi * 8) ^ swu)];
        }
#pragma unroll
      for (int nf = 0; nf < 4; ++nf)
#pragma unroll
        for (int ks = 0; ks < 2; ++ks) {
          int r = wc * 64 + nf * 16 + lo;
          bfr[nf][ks] =
              *(const bf16x8*)&smem[d + 16384 + r * 64 + ((ks * 32 + hi * 8) ^ swu)];
        }
      if (T + 1 < NKT) stage(T + 1, 3);
      __builtin_amdgcn_s_setprio(1);
#pragma unroll
      for (int mi = 0; mi < 2; ++mi)
#pragma unroll
        for (int nf = 0; nf < 4; ++nf)
#pragma unroll
          for (int ks = 0; ks < 2; ++ks)
            acc[mi][nf] = __builtin_amdgcn_mfma_f32_16x16x32_bf16(
                af[mi][ks], bfr[nf][ks], acc[mi][nf], 0, 0, 0);
      __builtin_amdgcn_s_setprio(0);
    }
#pragma unroll
    for (int p = 1; p < 4; ++p) {  // phases 1..3
      bf16x8 af[2][2];
#pragma unroll
      for (int mi = 0; mi < 2; ++mi)
#pragma unroll
        for (int ks = 0; ks < 2; ++ks) {
          int r = wr * 128 + (p * 2 + mi) * 16 + lo;
          af[mi][ks] = *(const bf16x8*)&smem[d + r * 64 + ((ks * 32 + hi * 8) ^ swu)];
        }
      __builtin_amdgcn_s_barrier();
      if (T + 2 < NKT) stage(T + 2, p - 1);
      __builtin_amdgcn_s_setprio(1);
#pragma unroll
      for (int mi = 0; mi < 2; ++mi)
#pragma unroll
        for (int nf = 0; nf < 4; ++nf)
#pragma unroll
          for (int ks = 0; ks < 2; ++ks)
            acc[p * 2 + mi][nf] = __builtin_amdgcn_mfma_f32_16x16x32_bf16(
                af[mi][ks], bfr[nf][ks], acc[p * 2 + mi][nf], 0, 0, 0);
      __builtin_amdgcn_s_setprio(0);
    }
  }
  __syncthreads();  // K-loop drained (vmcnt 0 at last head); reuse LDS

  if (SHARP) {
    float rs[8][4];
#pragma unroll
    for (int i = 0; i < 8; ++i)
#pragma unroll
      for (int j = 0; j < 4; ++j) rs[i][j] = 0.f;
    unsigned short* ep = smem;  // 256x256 u16 = 128 KB
#pragma unroll
    for (int mf = 0; mf < 8; ++mf)
#pragma unroll
      for (int nf = 0; nf < 4; ++nf)
#pragma unroll
        for (int j = 0; j < 4; ++j) {
          float s = sharpf(acc[mf][nf][j]);
          rs[mf][j] += s;
          int rl = wr * 128 + mf * 16 + (hi << 2) + j;
          int cl = (wc * 64 + nf * 16 + lo) ^ (((rl >> 2) & 3) << 4);
          ep[rl * 256 + cl] = f2bf(s);
        }
#pragma unroll
    for (int mf = 0; mf < 8; ++mf)
#pragma unroll
      for (int j = 0; j < 4; ++j) {
        float v = rs[mf][j];
        v += __shfl_xor(v, 1);
        v += __shfl_xor(v, 2);
        v += __shfl_xor(v, 4);
        v += __shfl_xor(v, 8);
        rs[mf][j] = v;
      }
    __syncthreads();
#pragma unroll
    for (int pass = 0; pass < 16; ++pass) {
      int idx = pass * 4096 + t * 8;
      int row = idx >> 8, col = idx & 255;
      int phys = row * 256 + (col ^ (((row >> 2) & 3) << 4));
      *(ushort8*)&wout[(size_t)(m0 + row) * C_DIM + n0 + col] =
          *(const ushort8*)&ep[phys];
    }
    __syncthreads();
    float* rbuf = (float*)smem;  // [4][256]
    if (lo == 0) {
#pragma unroll
      for (int mf = 0; mf < 8; ++mf)
#pragma unroll
        for (int j = 0; j < 4; ++j)
          rbuf[wc * 256 + wr * 128 + mf * 16 + (hi << 2) + j] = rs[mf][j];
    }
    __syncthreads();
    if (t < 256) {
      float v = (rbuf[t] + rbuf[256 + t]) + (rbuf[512 + t] + rbuf[768 + t]);
      rsum[(size_t)(wg & 3) * B_DIM + m0 + t] = v;  // rsum = rsum_part here
    }
  } else {
    // rinv from the 4 rowsum partials (L2-hot, replaces reduce kernel)
    float rinv[8][4];
#pragma unroll
    for (int mf = 0; mf < 8; ++mf) {
      int base = m0 + wr * 128 + mf * 16 + (hi << 2);
      float4 p0 = *(const float4*)&rsum[base];
      float4 p1 = *(const float4*)&rsum[B_DIM + base];
      float4 p2 = *(const float4*)&rsum[2 * B_DIM + base];
      float4 p3 = *(const float4*)&rsum[3 * B_DIM + base];
      rinv[mf][0] = __builtin_amdgcn_rcpf((p0.x + p1.x) + (p2.x + p3.x));
      rinv[mf][1] = __builtin_amdgcn_rcpf((p0.y + p1.y) + (p2.y + p3.y));
      rinv[mf][2] = __builtin_amdgcn_rcpf((p0.z + p1.z) + (p2.z + p3.z));
      rinv[mf][3] = __builtin_amdgcn_rcpf((p0.w + p1.w) + (p2.w + p3.w));
    }
#pragma unroll
    for (int mf = 0; mf < 8; ++mf)
#pragma unroll
      for (int nf = 0; nf < 4; ++nf)
#pragma unroll
        for (int j = 0; j < 4; ++j)
          fout[(size_t)(m0 + wr * 128 + mf * 16 + (hi << 2) + j) * C_DIM +
               n0 + wc * 64 + nf * 16 + lo] = acc[mf][nf][j] * rinv[mf][j];
  }
}

extern "C" void kernel_launch(void* const* d_in, const int* in_sizes, int n_in,
                              void* d_out, int out_size, void* d_ws, size_t ws_size,
                              hipStream_t stream) {
  const float* query = (const float*)d_in[0];
  const float* key = (const float*)d_in[1];
  const float* val = (const float*)d_in[2];
  float* out = (float*)d_out;
  const int B = in_sizes[0] / D_DIM;  // 65536

  char* ws = (char*)d_ws;
  unsigned short* kb = (unsigned short*)(ws);                         // 1 MB
  unsigned short* vbT = (unsigned short*)(ws + (1ull << 20));         // 2 MB
  float* rsum_part = (float*)(ws + 3ull * (1ull << 20));              // 1 MB
  unsigned short* qb = (unsigned short*)(ws + 4ull * (1ull << 20));   // 64 MB
  unsigned short* wbf = (unsigned short*)(ws + 68ull * (1ull << 20)); // 128 MB

  prep_kernel<<<dim3(17664), dim3(256), 0, stream>>>(query, key, val, qb, kb, vbT);

  dim3 grid((B / 256) * (C_DIM / 256));  // 1024 blocks
  gemm256_kernel<D_DIM, true><<<grid, dim3(512), 0, stream>>>(qb, kb, wbf, rsum_part, nullptr);
  gemm256_kernel<C_DIM, false><<<grid, dim3(512), 0, stream>>>(wbf, vbT, nullptr, rsum_part, out);
}